// Round 3
// baseline (41117.838 us; speedup 1.0000x reference)
//
#include <hip/hip_runtime.h>

#define T_STEPS 16384
#define N 2048
#define COLS_PER_BLK 8
#define NBLK (N / COLS_PER_BLK)   // 256 blocks, one per CU
#define THREADS 256
#define FLAG_STRIDE 16            // dwords -> 64B between flag lines
#define FLAGS_BYTES (NBLK * FLAG_STRIDE * 4)   // 16 KB

// ---------------------------------------------------------------------------
// Exchange protocol (no counter barrier):
//   publish p (p>=0): g-state entering step p, stored in gbuf[p&1].
//   flag[b] == p+1  <=>  block b has completed publish p (flags monotonic).
//   step t: wait all flags >= t+1, read gbuf[t&1]; at end store g into
//   gbuf[(t+1)&1], drain (syncthreads' vmcnt(0)), store flag = t+2.
//   2-buffer safety: publish p+2 (aliases p) only starts after ALL flags
//   >= p+2, i.e. every block finished step p+1's wait => done reading p.
// All cross-block data uses agent-scope relaxed atomics (sc0/sc1 coherent
// ops through the coherence point -- per-XCD L2s are not coherent).
// ---------------------------------------------------------------------------

__global__ void __launch_bounds__(THREADS, 1)
lif_kernel(const float* __restrict__ x_in, const float* __restrict__ w,
           const float* __restrict__ E_L, const float* __restrict__ tau_m,
           const float* __restrict__ R_I, const float* __restrict__ tau_g,
           const float* __restrict__ v0,  const float* __restrict__ g0,
           float* __restrict__ out, float* gbufA, float* gbufB,
           unsigned* flags)
{
    __shared__ float w_lds[COLS_PER_BLK][N];   // 64 KB: one-time staging
    __shared__ float g_lds[N];                 // 8 KB: per-step g broadcast

    const int tid = threadIdx.x;
    const int blk = blockIdx.x;
    const int j0  = blk * COLS_PER_BLK;

    // ---- one-time: stage w columns (transposed) into LDS, diagonal zeroed ----
    for (int r8 = 0; r8 < 8; ++r8) {
        int i = r8 * THREADS + tid;
        const float4* wrow = reinterpret_cast<const float4*>(w + (size_t)i * N + j0);
        float4 a = wrow[0];
        float4 b = wrow[1];
        float vals[8] = {a.x, a.y, a.z, a.w, b.x, b.y, b.z, b.w};
        #pragma unroll
        for (int jc = 0; jc < 8; ++jc)
            w_lds[jc][i] = (i == j0 + jc) ? 0.0f : vals[jc];
    }
    __syncthreads();

    // 32-lane group per output neuron
    const int col = tid >> 5;   // 0..7
    const int s   = tid & 31;   // lane in group
    const int j   = j0 + col;

    // ---- one-time: own w slice into registers (64 floats/lane) ----
    float4 wreg[16];
    #pragma unroll
    for (int k = 0; k < 16; ++k)
        wreg[k] = *reinterpret_cast<const float4*>(&w_lds[col][s * 4 + k * 128]);

    // persistent neuron state in owner-lane (s==0) registers
    float v_st = 0.f, g_st = 0.f, eL = 0.f, tm = 1.f, ri = 0.f, tg = 1.f;
    if (s == 0) {
        v_st = v0[j]; g_st = g0[j];
        eL = E_L[j]; tm = tau_m[j]; ri = R_I[j]; tg = tau_g[j];
        // publish 0: g0 into buffer A
        __hip_atomic_store(&gbufA[j], g_st, __ATOMIC_RELAXED,
                           __HIP_MEMORY_SCOPE_AGENT);
    }
    __syncthreads();   // each wave drains vmcnt before barrier => g0 visible
    if (tid == 0)
        __hip_atomic_store(&flags[blk * FLAG_STRIDE], 1u, __ATOMIC_RELAXED,
                           __HIP_MEMORY_SCOPE_AGENT);

    float xv = (s == 0) ? x_in[j] : 0.f;   // t=0 input prefetched

    for (int t = 0; t < T_STEPS; ++t) {
        const float* gsrc = (t & 1) ? gbufB : gbufA;
        float*       gdst = (t & 1) ? gbufA : gbufB;

        // ---- wait: all 256 publishes >= t+1 (wave 0 polls 4 flags/lane) ----
        if (tid < 64) {
            const unsigned tgt = (unsigned)(t + 1);
            for (;;) {
                unsigned f0 = __hip_atomic_load(&flags[(tid      ) * FLAG_STRIDE],
                                                __ATOMIC_RELAXED, __HIP_MEMORY_SCOPE_AGENT);
                unsigned f1 = __hip_atomic_load(&flags[(tid +  64) * FLAG_STRIDE],
                                                __ATOMIC_RELAXED, __HIP_MEMORY_SCOPE_AGENT);
                unsigned f2 = __hip_atomic_load(&flags[(tid + 128) * FLAG_STRIDE],
                                                __ATOMIC_RELAXED, __HIP_MEMORY_SCOPE_AGENT);
                unsigned f3 = __hip_atomic_load(&flags[(tid + 192) * FLAG_STRIDE],
                                                __ATOMIC_RELAXED, __HIP_MEMORY_SCOPE_AGENT);
                unsigned fm = min(min(f0, f1), min(f2, f3));
                if (__all(fm >= tgt)) break;
                __builtin_amdgcn_s_sleep(1);   // ~64 cy backoff
            }
        }
        __syncthreads();   // A: other waves join the poll result

        // ---- gather g (coherent, 8 floats/thread) -> LDS ----
        float gv[8];
        #pragma unroll
        for (int u = 0; u < 8; ++u)
            gv[u] = __hip_atomic_load((const float*)&gsrc[tid + u * 256],
                                      __ATOMIC_RELAXED, __HIP_MEMORY_SCOPE_AGENT);
        #pragma unroll
        for (int u = 0; u < 8; ++u)
            g_lds[tid + u * 256] = gv[u];   // stride-1 across lanes: conflict-free
        __syncthreads();   // B

        // ---- I[j] partials: 64 rows/lane, w in regs, g from LDS ----
        float4 acc = {0.f, 0.f, 0.f, 0.f};
        #pragma unroll
        for (int k = 0; k < 16; ++k) {
            float4 g4 = *reinterpret_cast<const float4*>(&g_lds[s * 4 + k * 128]);
            acc.x = fmaf(wreg[k].x, g4.x, acc.x);
            acc.y = fmaf(wreg[k].y, g4.y, acc.y);
            acc.z = fmaf(wreg[k].z, g4.z, acc.z);
            acc.w = fmaf(wreg[k].w, g4.w, acc.w);
        }
        float sum = (acc.x + acc.y) + (acc.z + acc.w);
        #pragma unroll
        for (int m = 16; m >= 1; m >>= 1)
            sum += __shfl_xor(sum, m, 64);   // masks <=16: stays in 32-lane group

        // ---- neuron update + publish (owner lane only) ----
        float soft = 0.f;
        if (s == 0) {
            float I      = fmaf(0.9f, xv, sum);
            float v_next = v_st + (eL - v_st + I * ri) / tm;
            soft         = 1.0f / (1.0f + expf(30.0f - v_next)); // sigmoid(v-30)
            bool  spiked = v_next >= 30.0f;
            v_st = spiked ? eL : v_next;
            g_st = spiked ? 1.0f : (g_st - g_st / tg);
            __hip_atomic_store(&gdst[j], g_st, __ATOMIC_RELAXED,
                               __HIP_MEMORY_SCOPE_AGENT);
        }
        __syncthreads();   // C: all waves' g stores drained (vmcnt(0) pre-barrier)

        if (tid == 0)      // signal publish t+1 complete
            __hip_atomic_store(&flags[blk * FLAG_STRIDE], (unsigned)(t + 2),
                               __ATOMIC_RELAXED, __HIP_MEMORY_SCOPE_AGENT);

        // off the critical path: result store + next input prefetch overlap
        // the other blocks' polls (plain cached ops, flushed at kernel end)
        if (s == 0) {
            out[(size_t)t * N + j] = soft;
            if (t + 1 < T_STEPS) xv = x_in[(size_t)(t + 1) * N + j];
        }
    }
}

extern "C" void kernel_launch(void* const* d_in, const int* in_sizes, int n_in,
                              void* d_out, int out_size, void* d_ws, size_t ws_size,
                              hipStream_t stream) {
    const float* x_in  = (const float*)d_in[0];
    const float* w     = (const float*)d_in[1];
    const float* E_L   = (const float*)d_in[2];
    const float* tau_m = (const float*)d_in[3];
    const float* R_I   = (const float*)d_in[4];
    const float* tau_g = (const float*)d_in[5];
    const float* v0    = (const float*)d_in[6];
    const float* g0    = (const float*)d_in[7];
    float* out = (float*)d_out;

    // d_ws: [0,16K) flags | [16K,+8K) gbufA | [24K,+8K) gbufB
    unsigned* flags = (unsigned*)d_ws;
    float* gA = (float*)((char*)d_ws + FLAGS_BYTES);
    float* gB = (float*)((char*)d_ws + FLAGS_BYTES + N * sizeof(float));

    // d_ws re-poisoned to 0xAA before every timed call: flags must start at 0.
    hipMemsetAsync(d_ws, 0, FLAGS_BYTES, stream);

    void* args[] = {(void*)&x_in, (void*)&w, (void*)&E_L, (void*)&tau_m,
                    (void*)&R_I, (void*)&tau_g, (void*)&v0, (void*)&g0,
                    (void*)&out, (void*)&gA, (void*)&gB, (void*)&flags};
    hipLaunchCooperativeKernel((const void*)lif_kernel, dim3(NBLK), dim3(THREADS),
                               args, 0, stream);
}